// Round 4
// baseline (778.407 us; speedup 1.0000x reference)
//
#include <hip/hip_runtime.h>
#include <hip/hip_bf16.h>

typedef long long TLONG;
typedef float  f32x4_t  __attribute__((ext_vector_type(4)));
typedef short  s16x8_t  __attribute__((ext_vector_type(8)));
typedef short  s16x4_t  __attribute__((ext_vector_type(4)));
typedef __bf16 bf16x8_t __attribute__((ext_vector_type(8)));

#define MDIM 32768
#define NDIM 1024
#define KDIM 1024
#define EPSV 1e-6f

__device__ __forceinline__ unsigned short f2bf_bits(float f) {
  __hip_bfloat16 h = __float2bfloat16(f);
  return __builtin_bit_cast(unsigned short, h);
}
__device__ __forceinline__ float bf2f(unsigned short u) {
  unsigned int x = ((unsigned int)u) << 16;
  return __builtin_bit_cast(float, x);
}
// async global->LDS, 16B per lane. LDS dest must be wave-uniform base + lane*16.
__device__ __forceinline__ void load_lds16(const void* g, void* l) {
  __builtin_amdgcn_global_load_lds((const __attribute__((address_space(1))) void*)g,
                                   (__attribute__((address_space(3))) void*)l, 16, 0, 0);
}

// ---------------------------------------------------------------- convert
__global__ __launch_bounds__(256) void convert_f32_bf16(
    const float* __restrict__ in, unsigned short* __restrict__ out, TLONG n) {
  TLONG i = ((TLONG)blockIdx.x * blockDim.x + threadIdx.x) * 8;
  const TLONG stride = (TLONG)gridDim.x * blockDim.x * 8;
  for (; i < n; i += stride) {
    f32x4_t a = *reinterpret_cast<const f32x4_t*>(in + i);
    f32x4_t b = *reinterpret_cast<const f32x4_t*>(in + i + 4);
    s16x8_t o;
    o[0] = (short)f2bf_bits(a[0]); o[1] = (short)f2bf_bits(a[1]);
    o[2] = (short)f2bf_bits(a[2]); o[3] = (short)f2bf_bits(a[3]);
    o[4] = (short)f2bf_bits(b[0]); o[5] = (short)f2bf_bits(b[1]);
    o[6] = (short)f2bf_bits(b[2]); o[7] = (short)f2bf_bits(b[3]);
    *reinterpret_cast<s16x8_t*>(out + i) = o;
  }
}

// ---------------------------------------------------------------- GEMM 256x256, 8-phase
// C[m][n] = f(sum_k A[m][k]*W[n][k] + bias[n]); M=32768, N=K=1024.
// BM=BN=256, BK=64; 512 thr = 8 waves (2 M x 4 N); wave tile 128x64.
// LDS 128 KiB = 2 buf x (A 32KB + B 32KB); each region split in 2 halves (128 rows).
// Per K-tile: 4 phases {ds_read subtile | stage 1 half-tile | barrier | lgkm0 |
// setprio+16 MFMA | barrier}. Half-tile stage stream runs 2 half-tiles ahead;
// ONE counted vmcnt(4) per K-tile (phase D) - never drained to 0 in-loop (T4).
// Stage schedule (kt, p=kt&1): phA->(kt+1).Bh0, phB->(kt+1).Bh1 (buf 1-p, reads
// done at kt-1 phB); phC->(kt+2).Ah0, phD->(kt+2).Ah1 (buf p, reads done at phB).
// At phD vmcnt(4): in-flight = kt+2's 2 A-halves; all of kt+1 has landed.
template <int FMAP, int OUT>
__global__ __launch_bounds__(512, 2) void gemm256(
    const unsigned short* __restrict__ A, const unsigned short* __restrict__ W,
    const float* __restrict__ bias, void* __restrict__ Cout) {
  __shared__ short lds[65536];                    // [2 buf][A 16384 | B 16384] shorts
  const int bid = blockIdx.x;                     // 512 blocks
  const int swz = (bid & 7) * 64 + (bid >> 3);    // XCD-chunked (512%8==0)
  const int mt = swz >> 2;                        // 0..127
  const int nt = swz & 3;                         // 0..3

  const int tid = threadIdx.x;
  const int lane = tid & 63;
  const int w = tid >> 6;
  const int wr = w >> 2, wc = w & 3;
  const int l15 = lane & 15, lh = lane >> 4;

  const int arow0 = mt * 256, brow0 = nt * 256;

  // stage one 128-row half-tile (2 x 16B per thread), linear LDS dest,
  // inverse-swizzled global source (slot ps holds col-group ps^(r&7)).
  auto stage_half = [&](const unsigned short* __restrict__ src, int ldsOff,
                        int grow, int k0) {
#pragma unroll
    for (int i = 0; i < 2; ++i) {
      const int c = i * 512 + tid;                // 0..1023
      const int r = c >> 3, ps = c & 7;
      load_lds16(src + (grow + r) * KDIM + k0 + ((ps ^ (r & 7)) * 8),
                 &lds[ldsOff + c * 8]);
    }
  };

  f32x4_t acc[8][4];
#pragma unroll
  for (int m = 0; m < 8; ++m)
#pragma unroll
    for (int n = 0; n < 4; ++n) acc[m][n] = (f32x4_t)0.0f;

  s16x8_t Af[8][2], Bf[4][2];

  auto rdA = [&](int pb, int m, int ks) -> s16x8_t {
    const int row = wr * 128 + m * 16 + l15;
    return *reinterpret_cast<const s16x8_t*>(
        &lds[pb + row * 64 + (((ks * 4 + lh) ^ (row & 7)) * 8)]);
  };
  auto rdB = [&](int pb, int n, int ks) -> s16x8_t {
    const int row = wc * 64 + n * 16 + l15;
    return *reinterpret_cast<const s16x8_t*>(
        &lds[pb + 16384 + row * 64 + (((ks * 4 + lh) ^ (row & 7)) * 8)]);
  };
  auto quad = [&](int mb, int nl) {
    __builtin_amdgcn_s_setprio(1);
#pragma unroll
    for (int m = 0; m < 4; ++m)
#pragma unroll
      for (int n = 0; n < 2; ++n)
#pragma unroll
        for (int ks = 0; ks < 2; ++ks)
          acc[mb + m][nl + n] = __builtin_amdgcn_mfma_f32_16x16x32_bf16(
              __builtin_bit_cast(bf16x8_t, Af[mb + m][ks]),
              __builtin_bit_cast(bf16x8_t, Bf[nl + n][ks]),
              acc[mb + m][nl + n], 0, 0, 0);
    __builtin_amdgcn_s_setprio(0);
  };

  // prologue: kt0 all 4 halves -> buf0; kt1 A-halves -> buf1 (12 loads)
  stage_half(A, 0,             arow0,       0);
  stage_half(A, 8192,          arow0 + 128, 0);
  stage_half(W, 16384,         brow0,       0);
  stage_half(W, 16384 + 8192,  brow0 + 128, 0);
  stage_half(A, 32768,         arow0,       64);
  stage_half(A, 32768 + 8192,  arow0 + 128, 64);
  asm volatile("s_waitcnt vmcnt(4)" ::: "memory");   // kt0's 8 landed
  __builtin_amdgcn_sched_barrier(0);
  __builtin_amdgcn_s_barrier();

#pragma unroll 2
  for (int kt = 0; kt < 16; ++kt) {
    const int p = kt & 1;
    const int pb = p * 32768, qb = (1 - p) * 32768;
    const int k1 = ((kt + 1) & 15) * 64;
    const int k2 = ((kt + 2) & 15) * 64;
    // ---- phase A: read A m0-3 + B all; stage (kt+1).B half0
#pragma unroll
    for (int m = 0; m < 4; ++m)
#pragma unroll
      for (int ks = 0; ks < 2; ++ks) Af[m][ks] = rdA(pb, m, ks);
#pragma unroll
    for (int n = 0; n < 4; ++n)
#pragma unroll
      for (int ks = 0; ks < 2; ++ks) Bf[n][ks] = rdB(pb, n, ks);
    stage_half(W, qb + 16384, brow0, k1);
    __builtin_amdgcn_s_barrier();
    asm volatile("s_waitcnt lgkmcnt(0)" ::: "memory");
    __builtin_amdgcn_sched_barrier(0);
    quad(0, 0);
    __builtin_amdgcn_s_barrier();
    // ---- phase B: read A m4-7; stage (kt+1).B half1
#pragma unroll
    for (int m = 0; m < 4; ++m)
#pragma unroll
      for (int ks = 0; ks < 2; ++ks) Af[4 + m][ks] = rdA(pb, 4 + m, ks);
    stage_half(W, qb + 16384 + 8192, brow0 + 128, k1);
    __builtin_amdgcn_s_barrier();
    asm volatile("s_waitcnt lgkmcnt(0)" ::: "memory");   // all buf-p reads done
    __builtin_amdgcn_sched_barrier(0);
    quad(0, 2);
    __builtin_amdgcn_s_barrier();
    // ---- phase C: stage (kt+2).A half0 into freed buf p
    stage_half(A, pb, arow0, k2);
    __builtin_amdgcn_s_barrier();
    quad(4, 0);
    __builtin_amdgcn_s_barrier();
    // ---- phase D: stage (kt+2).A half1; counted vmcnt
    stage_half(A, pb + 8192, arow0 + 128, k2);
    __builtin_amdgcn_s_barrier();
    quad(4, 2);
    asm volatile("s_waitcnt vmcnt(4)" ::: "memory");     // kt+1 fully landed
    __builtin_amdgcn_sched_barrier(0);
    __builtin_amdgcn_s_barrier();
  }

  // epilogue: C/D layout col = lane&15, row = (lane>>4)*4 + j  [m89/m91]
#pragma unroll
  for (int n = 0; n < 4; ++n) {
    const int col = nt * 256 + wc * 64 + n * 16 + l15;
    const float bv = bias[col];
#pragma unroll
    for (int m = 0; m < 8; ++m) {
      const int row0 = mt * 256 + wr * 128 + m * 16 + lh * 4;
      if (OUT == 2) {
        const int b = row0 >> 13, tl = row0 & 8191;
        const int h = col >> 6, d = col & 63;
        s16x4_t o;
#pragma unroll
        for (int j = 0; j < 4; ++j) {
          float v = acc[m][n][j] + bv;
          if (FMAP) v = (v > 0.0f) ? (v + 1.0f) : __expf(v);
          o[j] = (short)f2bf_bits(v);
        }
        *reinterpret_cast<s16x4_t*>(
            reinterpret_cast<unsigned short*>(Cout) +
            (((b * 16 + h) * 64 + d) * 8192 + tl)) = o;
      } else {
#pragma unroll
        for (int j = 0; j < 4; ++j) {
          float v = acc[m][n][j] + bv;
          if (FMAP) v = (v > 0.0f) ? (v + 1.0f) : __expf(v);  // elu(x)+1
          if (OUT == 1)
            reinterpret_cast<float*>(Cout)[(row0 + j) * NDIM + col] = v;
          else
            reinterpret_cast<unsigned short*>(Cout)[(row0 + j) * NDIM + col] = f2bf_bits(v);
        }
      }
    }
  }
}

// ---------------------------------------------------------------- kv + k_sum (MFMA, streaming)
// Inputs transposed: kT[bh][d][8192 t], vT[bh][e][8192 t] (bf16).
__global__ __launch_bounds__(256) void kv_ksum_mfma(
    const unsigned short* __restrict__ kT, const unsigned short* __restrict__ vT,
    float* __restrict__ kvT, float* __restrict__ ksum) {
  const int bid = blockIdx.x;
  const int bh = bid >> 4, ch = bid & 15;
  const int tid = threadIdx.x;
  const int lane = tid & 63, w = tid >> 6;
  const int l15 = lane & 15, lh = lane >> 4;
  const int dblk = (w >> 1) * 32, eblk = (w & 1) * 32;

  f32x4_t acc[2][2];
#pragma unroll
  for (int m = 0; m < 2; ++m)
#pragma unroll
    for (int n = 0; n < 2; ++n) acc[m][n] = (f32x4_t)0.0f;
  float ks0 = 0.f, ks1 = 0.f;

  const int tbase = ch * 512 + lh * 8;
  const unsigned short* ka = kT + (bh * 64 + dblk + l15) * 8192 + tbase;
  const unsigned short* va = vT + (bh * 64 + eblk + l15) * 8192 + tbase;

  for (int t0 = 0; t0 < 512; t0 += 32) {
    s16x8_t ar[2], br[2];
#pragma unroll
    for (int m = 0; m < 2; ++m)
      ar[m] = *reinterpret_cast<const s16x8_t*>(ka + m * 16 * 8192 + t0);
#pragma unroll
    for (int n = 0; n < 2; ++n)
      br[n] = *reinterpret_cast<const s16x8_t*>(va + n * 16 * 8192 + t0);
#pragma unroll
    for (int m = 0; m < 2; ++m)
#pragma unroll
      for (int n = 0; n < 2; ++n)
        acc[m][n] = __builtin_amdgcn_mfma_f32_16x16x32_bf16(
            __builtin_bit_cast(bf16x8_t, ar[m]),
            __builtin_bit_cast(bf16x8_t, br[n]), acc[m][n], 0, 0, 0);
    if (eblk == 0) {
#pragma unroll
      for (int i = 0; i < 8; ++i) ks0 += bf2f((unsigned short)ar[0][i]);
#pragma unroll
      for (int i = 0; i < 8; ++i) ks1 += bf2f((unsigned short)ar[1][i]);
    }
  }

  if (eblk == 0) {
    ks0 += __shfl_xor(ks0, 16); ks0 += __shfl_xor(ks0, 32);
    ks1 += __shfl_xor(ks1, 16); ks1 += __shfl_xor(ks1, 32);
    if (lh == 0) {
      atomicAdd(&ksum[bh * 64 + dblk + l15], ks0);
      atomicAdd(&ksum[bh * 64 + dblk + 16 + l15], ks1);
    }
  }
#pragma unroll
  for (int n = 0; n < 2; ++n) {
    const int e = eblk + n * 16 + l15;
#pragma unroll
    for (int m = 0; m < 2; ++m) {
      const int d0 = dblk + m * 16 + lh * 4;
#pragma unroll
      for (int j = 0; j < 4; ++j)
        atomicAdd(&kvT[(bh * 64 + e) * 64 + d0 + j], acc[m][n][j]);
    }
  }
}

// ---------------------------------------------------------------- out = q@kv / (q.ksum+eps)
__global__ __launch_bounds__(256) void attn_apply_kernel(
    const unsigned short* __restrict__ qf, const float* __restrict__ kvT,
    const float* __restrict__ ksum, unsigned short* __restrict__ att) {
  const int bid = blockIdx.x;                     // 2048
  const int swz = (bid & 7) * 256 + (bid >> 3);
  const int bh = swz >> 5;
  const int tile = swz & 31;
  const int b = bh >> 4, h = bh & 15;
  const int tid = threadIdx.x;
  const int lane = tid & 63, w = tid >> 6;
  const int l15 = lane & 15, lh = lane >> 4;

  float ksr[16];
#pragma unroll
  for (int i = 0; i < 16; ++i) ksr[i] = ksum[bh * 64 + lh * 16 + i];

  bf16x8_t bfrag[2][4];
#pragma unroll
  for (int ks2 = 0; ks2 < 2; ++ks2)
#pragma unroll
    for (int n = 0; n < 4; ++n) {
      const float* p = kvT + (bh * 64 + n * 16 + l15) * 64 + ks2 * 32 + lh * 8;
      f32x4_t p0 = *reinterpret_cast<const f32x4_t*>(p);
      f32x4_t p1 = *reinterpret_cast<const f32x4_t*>(p + 4);
      s16x8_t t;
      t[0] = (short)f2bf_bits(p0[0]); t[1] = (short)f2bf_bits(p0[1]);
      t[2] = (short)f2bf_bits(p0[2]); t[3] = (short)f2bf_bits(p0[3]);
      t[4] = (short)f2bf_bits(p1[0]); t[5] = (short)f2bf_bits(p1[1]);
      t[6] = (short)f2bf_bits(p1[2]); t[7] = (short)f2bf_bits(p1[3]);
      bfrag[ks2][n] = __builtin_bit_cast(bf16x8_t, t);
    }

  const int rbase = b * 8192 + tile * 256 + w * 64;
  f32x4_t acc[4][4];
#pragma unroll
  for (int m = 0; m < 4; ++m)
#pragma unroll
    for (int n = 0; n < 4; ++n) acc[m][n] = (f32x4_t)0.0f;
  float rden[4][4];

#pragma unroll
  for (int m = 0; m < 4; ++m) {
    const int row = rbase + m * 16 + l15;
    const unsigned short* qrow = qf + row * 1024 + h * 64;
    bf16x8_t afr[2];
#pragma unroll
    for (int ks2 = 0; ks2 < 2; ++ks2)
      afr[ks2] = __builtin_bit_cast(bf16x8_t,
          *reinterpret_cast<const s16x8_t*>(qrow + ks2 * 32 + lh * 8));
    s16x8_t qa = *reinterpret_cast<const s16x8_t*>(qrow + lh * 16);
    s16x8_t qb = *reinterpret_cast<const s16x8_t*>(qrow + lh * 16 + 8);
    float part = 0.f;
#pragma unroll
    for (int i = 0; i < 8; ++i) part += bf2f((unsigned short)qa[i]) * ksr[i];
#pragma unroll
    for (int i = 0; i < 8; ++i) part += bf2f((unsigned short)qb[i]) * ksr[8 + i];
    part += __shfl_xor(part, 16);
    part += __shfl_xor(part, 32);
#pragma unroll
    for (int j = 0; j < 4; ++j) {
      float dj = __shfl(part, lh * 4 + j);
      rden[m][j] = 1.0f / (dj + EPSV);
    }
#pragma unroll
    for (int ks2 = 0; ks2 < 2; ++ks2)
#pragma unroll
      for (int n = 0; n < 4; ++n)
        acc[m][n] = __builtin_amdgcn_mfma_f32_16x16x32_bf16(afr[ks2], bfrag[ks2][n], acc[m][n], 0, 0, 0);
  }

#pragma unroll
  for (int m = 0; m < 4; ++m)
#pragma unroll
    for (int n = 0; n < 4; ++n) {
      const int col = h * 64 + n * 16 + l15;
#pragma unroll
      for (int j = 0; j < 4; ++j) {
        const int row = rbase + m * 16 + lh * 4 + j;
        att[row * 1024 + col] = f2bf_bits(acc[m][n][j] * rden[m][j]);
      }
    }
}

// ---------------------------------------------------------------- launch
extern "C" void kernel_launch(void* const* d_in, const int* in_sizes, int n_in,
                              void* d_out, int out_size, void* d_ws, size_t ws_size,
                              hipStream_t stream) {
  const float* query = (const float*)d_in[0];
  const float* key   = (const float*)d_in[1];
  const float* value = (const float*)d_in[2];
  const float* Wq = (const float*)d_in[3];
  const float* bq = (const float*)d_in[4];
  const float* Wk = (const float*)d_in[5];
  const float* bk = (const float*)d_in[6];
  const float* Wv = (const float*)d_in[7];
  const float* bv = (const float*)d_in[8];
  const float* Wo = (const float*)d_in[9];
  const float* bo = (const float*)d_in[10];
  float* out = (float*)d_out;

  if (ws_size < 277889024ULL) return;
  char* ws = (char*)d_ws;
  unsigned short* Vbf = (unsigned short*)(ws + 0);          // value bf16; reused as att
  unsigned short* qf  = (unsigned short*)(ws + 67108864);
  unsigned short* kTf = (unsigned short*)(ws + 134217728);  // k transposed [b][h][d][t]
  unsigned short* vTf = (unsigned short*)(ws + 201326592);  // v transposed
  unsigned short* Wqb = (unsigned short*)(ws + 268435456);
  unsigned short* Wkb = Wqb + 1048576;
  unsigned short* Wvb = Wkb + 1048576;
  unsigned short* Wob = Wvb + 1048576;
  float* kvT  = (float*)(ws + 276824064);
  float* ksum = (float*)(ws + 277872640);

  unsigned short* Qbf = (unsigned short*)d_out;   // d_out doubles as bf16 scratch
  unsigned short* Kbf = Qbf + 33554432;

  hipMemsetAsync(kvT, 0, (size_t)(64 * 64 * 64 + 64 * 64) * sizeof(float), stream);

  convert_f32_bf16<<<2048, 256, 0, stream>>>(query, Qbf, 33554432LL);
  convert_f32_bf16<<<2048, 256, 0, stream>>>(key,   Kbf, 33554432LL);
  convert_f32_bf16<<<2048, 256, 0, stream>>>(value, Vbf, 33554432LL);
  convert_f32_bf16<<<512, 256, 0, stream>>>(Wq, Wqb, 1048576LL);
  convert_f32_bf16<<<512, 256, 0, stream>>>(Wk, Wkb, 1048576LL);
  convert_f32_bf16<<<512, 256, 0, stream>>>(Wv, Wvb, 1048576LL);
  convert_f32_bf16<<<512, 256, 0, stream>>>(Wo, Wob, 1048576LL);

  gemm256<1, 0><<<512, 512, 0, stream>>>(Qbf, Wqb, bq, qf);   // q row-major
  gemm256<1, 2><<<512, 512, 0, stream>>>(Kbf, Wkb, bk, kTf);  // k transposed
  gemm256<0, 2><<<512, 512, 0, stream>>>(Vbf, Wvb, bv, vTf);  // v transposed

  kv_ksum_mfma<<<1024, 256, 0, stream>>>(kTf, vTf, kvT, ksum);

  attn_apply_kernel<<<2048, 256, 0, stream>>>(qf, kvT, ksum, Vbf);  // att -> Vbf

  gemm256<0, 1><<<512, 512, 0, stream>>>(Vbf, Wob, bo, out);  // final -> f32
}

// Round 5
// 600.332 us; speedup vs baseline: 1.2966x; 1.2966x over previous
//
#include <hip/hip_runtime.h>
#include <hip/hip_bf16.h>

typedef long long TLONG;
typedef float  f32x4_t  __attribute__((ext_vector_type(4)));
typedef short  s16x8_t  __attribute__((ext_vector_type(8)));
typedef short  s16x4_t  __attribute__((ext_vector_type(4)));
typedef __bf16 bf16x8_t __attribute__((ext_vector_type(8)));

#define MDIM 32768
#define NDIM 1024
#define KDIM 1024
#define EPSV 1e-6f

#define BARRIER() asm volatile("s_barrier" ::: "memory")
#define SBAR() __builtin_amdgcn_sched_barrier(0)

__device__ __forceinline__ unsigned short f2bf_bits(float f) {
  __hip_bfloat16 h = __float2bfloat16(f);
  return __builtin_bit_cast(unsigned short, h);
}
__device__ __forceinline__ float bf2f(unsigned short u) {
  unsigned int x = ((unsigned int)u) << 16;
  return __builtin_bit_cast(float, x);
}
// async global->LDS, 16B per lane. LDS dest must be wave-uniform base + lane*16.
__device__ __forceinline__ void load_lds16(const void* g, void* l) {
  __builtin_amdgcn_global_load_lds((const __attribute__((address_space(1))) void*)g,
                                   (__attribute__((address_space(3))) void*)l, 16, 0, 0);
}

__device__ __forceinline__ void conv8(const float* __restrict__ in,
                                      unsigned short* __restrict__ out, TLONG i) {
  f32x4_t a = *reinterpret_cast<const f32x4_t*>(in + i);
  f32x4_t b = *reinterpret_cast<const f32x4_t*>(in + i + 4);
  s16x8_t o;
  o[0] = (short)f2bf_bits(a[0]); o[1] = (short)f2bf_bits(a[1]);
  o[2] = (short)f2bf_bits(a[2]); o[3] = (short)f2bf_bits(a[3]);
  o[4] = (short)f2bf_bits(b[0]); o[5] = (short)f2bf_bits(b[1]);
  o[6] = (short)f2bf_bits(b[2]); o[7] = (short)f2bf_bits(b[3]);
  *reinterpret_cast<s16x8_t*>(out + i) = o;
}

// ---------------------------------------------------------------- converts
// 3 big activations (33.5M elems each), 6144 blocks (2048 per array, x8 grid-stride)
__global__ __launch_bounds__(256) void convert3_f32_bf16(
    const float* __restrict__ a, const float* __restrict__ b, const float* __restrict__ c,
    unsigned short* __restrict__ oa, unsigned short* __restrict__ ob,
    unsigned short* __restrict__ oc) {
  int blk = blockIdx.x;
  const float* in; unsigned short* out;
  if (blk < 2048)      { in = a; out = oa; }
  else if (blk < 4096) { in = b; out = ob; blk -= 2048; }
  else                 { in = c; out = oc; blk -= 4096; }
  const TLONG n = 33554432LL;
  TLONG i = ((TLONG)blk * 256 + threadIdx.x) * 8;
  const TLONG stride = 2048LL * 256 * 8;
  for (; i < n; i += stride) conv8(in, out, i);
}
// 4 weights (1M elems each), 2048 blocks: 512*256*8 = exactly 1M per range
__global__ __launch_bounds__(256) void convertW_f32_bf16(
    const float* __restrict__ a, const float* __restrict__ b, const float* __restrict__ c,
    const float* __restrict__ d, unsigned short* __restrict__ oa,
    unsigned short* __restrict__ ob, unsigned short* __restrict__ oc,
    unsigned short* __restrict__ od) {
  int blk = blockIdx.x;
  const float* in; unsigned short* out;
  if (blk < 512)       { in = a; out = oa; }
  else if (blk < 1024) { in = b; out = ob; blk -= 512; }
  else if (blk < 1536) { in = c; out = oc; blk -= 1024; }
  else                 { in = d; out = od; blk -= 1536; }
  TLONG i = ((TLONG)blk * 256 + threadIdx.x) * 8;
  conv8(in, out, i);
}

// ---------------------------------------------------------------- GEMM 256x256, counted-wait phases
// C[m][n] = f(sum_k A[m][k]*W[n][k] + bias[n]); M=32768, N=K=1024.
// BM=BN=256, BK=64; 512 thr = 8 waves (2M x 4N); wave tile 128x64.
// LDS 128 KiB = 2 buf x (A 32KB | B 32KB), halves of 128 rows.
// Per K-tile, 4 phases. Phase A issues ALL 24 ds_reads in need-order
// [Af0-3,Bf0-1 | Af4-7 | Bf2-3] (groups pinned by sched_barrier); waits are
// COUNTED: lgkm(12) -> quad(0,0); lgkm(4) -> quad(4,0); lgkm(0, only 4 left)
// -> quad(0,2); none -> quad(4,2). One counted vmcnt(4) per K-tile (T4).
// Stage stream: phA/phB -> (kt+1).B halves (other buf, reads drained last kt);
// phC/phD -> (kt+2).A halves (this buf; Af0-3 done at phA, Af4-7 at phB).
template <int FMAP, int OUT>
__global__ __launch_bounds__(512, 2) void gemm256(
    const unsigned short* __restrict__ A, const unsigned short* __restrict__ W,
    const float* __restrict__ bias, void* __restrict__ Cout) {
  __shared__ short lds[65536];                    // [2 buf][A 16384 | B 16384] shorts
  const int bid = blockIdx.x;                     // 512 blocks
  const int swz = (bid & 7) * 64 + (bid >> 3);    // XCD-chunked (512%8==0)
  const int mt = swz >> 2;                        // 0..127
  const int nt = swz & 3;                         // 0..3

  const int tid = threadIdx.x;
  const int lane = tid & 63;
  const int w = tid >> 6;
  const int wr = w >> 2, wc = w & 3;
  const int l15 = lane & 15, lh = lane >> 4;

  const int arow0 = mt * 256, brow0 = nt * 256;

  auto stage_half = [&](const unsigned short* __restrict__ src, int ldsOff,
                        int grow, int k0) {
#pragma unroll
    for (int i = 0; i < 2; ++i) {
      const int c = i * 512 + tid;                // 0..1023
      const int r = c >> 3, ps = c & 7;
      load_lds16(src + (grow + r) * KDIM + k0 + ((ps ^ (r & 7)) * 8),
                 &lds[ldsOff + c * 8]);
    }
  };

  f32x4_t acc[8][4];
#pragma unroll
  for (int m = 0; m < 8; ++m)
#pragma unroll
    for (int n = 0; n < 4; ++n) acc[m][n] = (f32x4_t)0.0f;

  s16x8_t Af[8][2], Bf[4][2];

  auto rdA = [&](int pb, int m, int ks) -> s16x8_t {
    const int row = wr * 128 + m * 16 + l15;
    return *reinterpret_cast<const s16x8_t*>(
        &lds[pb + row * 64 + (((ks * 4 + lh) ^ (row & 7)) * 8)]);
  };
  auto rdB = [&](int pb, int n, int ks) -> s16x8_t {
    const int row = wc * 64 + n * 16 + l15;
    return *reinterpret_cast<const s16x8_t*>(
        &lds[pb + 16384 + row * 64 + (((ks * 4 + lh) ^ (row & 7)) * 8)]);
  };
  auto quad = [&](int mb, int nl) {
    __builtin_amdgcn_s_setprio(1);
#pragma unroll
    for (int m = 0; m < 4; ++m)
#pragma unroll
      for (int n = 0; n < 2; ++n)
#pragma unroll
        for (int ks = 0; ks < 2; ++ks)
          acc[mb + m][nl + n] = __builtin_amdgcn_mfma_f32_16x16x32_bf16(
              __builtin_bit_cast(bf16x8_t, Af[mb + m][ks]),
              __builtin_bit_cast(bf16x8_t, Bf[nl + n][ks]),
              acc[mb + m][nl + n], 0, 0, 0);
    __builtin_amdgcn_s_setprio(0);
  };

  // prologue: kt0 all 4 halves -> buf0; kt1 A-halves -> buf1 (12 loads/thread)
  stage_half(A, 0,             arow0,       0);
  stage_half(A, 8192,          arow0 + 128, 0);
  stage_half(W, 16384,         brow0,       0);
  stage_half(W, 16384 + 8192,  brow0 + 128, 0);
  stage_half(A, 32768,         arow0,       64);
  stage_half(A, 32768 + 8192,  arow0 + 128, 64);
  asm volatile("s_waitcnt vmcnt(4)" ::: "memory");   // kt0's 8 landed; kt1.A in flight
  SBAR();
  BARRIER();

  for (int kt = 0; kt < 16; ++kt) {
    const int p = kt & 1;
    const int pb = p * 32768, qb = 32768 - pb;
    const int k1 = ((kt + 1) & 15) * 64;
    const int k2 = ((kt + 2) & 15) * 64;   // wrapped tail: junk reload, never read
    // ---- phase A: all 24 ds_reads (pinned groups); stage (kt+1).Bh0
#pragma unroll
    for (int m = 0; m < 4; ++m)
#pragma unroll
      for (int ks = 0; ks < 2; ++ks) Af[m][ks] = rdA(pb, m, ks);
#pragma unroll
    for (int n = 0; n < 2; ++n)
#pragma unroll
      for (int ks = 0; ks < 2; ++ks) Bf[n][ks] = rdB(pb, n, ks);
    SBAR();                                         // pin group 1 (12 reads)
#pragma unroll
    for (int m = 0; m < 4; ++m)
#pragma unroll
      for (int ks = 0; ks < 2; ++ks) Af[4 + m][ks] = rdA(pb, 4 + m, ks);
    SBAR();                                         // pin group 2 (8 reads)
#pragma unroll
    for (int n = 2; n < 4; ++n)
#pragma unroll
      for (int ks = 0; ks < 2; ++ks) Bf[n][ks] = rdB(pb, n, ks);
    SBAR();                                         // pin group 3 (4 reads)
    stage_half(W, qb + 16384, brow0, k1);
    BARRIER();
    asm volatile("s_waitcnt lgkmcnt(12)" ::: "memory");  // group 1 done
    SBAR();
    quad(0, 0);
    BARRIER();
    // ---- phase B: stage (kt+1).Bh1
    stage_half(W, qb + 16384 + 8192, brow0 + 128, k1);
    BARRIER();
    asm volatile("s_waitcnt lgkmcnt(4)" ::: "memory");   // + group 2 (Af4-7) done
    SBAR();
    quad(4, 0);
    BARRIER();
    // ---- phase C: stage (kt+2).Ah0 into freed rows 0-127 of buf p
    stage_half(A, pb, arow0, k2);
    BARRIER();
    asm volatile("s_waitcnt lgkmcnt(0)" ::: "memory");   // last 4 (Bf2-3) done
    SBAR();
    quad(0, 2);
    BARRIER();
    // ---- phase D: stage (kt+2).Ah1; counted vmcnt
    stage_half(A, pb + 8192, arow0 + 128, k2);
    BARRIER();
    quad(4, 2);
    asm volatile("s_waitcnt vmcnt(4)" ::: "memory");     // kt+1 fully landed
    SBAR();
    BARRIER();
  }

  // epilogue: C/D layout col = lane&15, row = (lane>>4)*4 + j  [m89/m91]
#pragma unroll
  for (int n = 0; n < 4; ++n) {
    const int col = nt * 256 + wc * 64 + n * 16 + l15;
    const float bv = bias[col];
#pragma unroll
    for (int m = 0; m < 8; ++m) {
      const int row0 = mt * 256 + wr * 128 + m * 16 + lh * 4;
      if (OUT == 2) {
        const int b = row0 >> 13, tl = row0 & 8191;
        const int h = col >> 6, d = col & 63;
        s16x4_t o;
#pragma unroll
        for (int j = 0; j < 4; ++j) {
          float v = acc[m][n][j] + bv;
          if (FMAP) v = (v > 0.0f) ? (v + 1.0f) : __expf(v);
          o[j] = (short)f2bf_bits(v);
        }
        *reinterpret_cast<s16x4_t*>(
            reinterpret_cast<unsigned short*>(Cout) +
            (((b * 16 + h) * 64 + d) * 8192 + tl)) = o;
      } else {
#pragma unroll
        for (int j = 0; j < 4; ++j) {
          float v = acc[m][n][j] + bv;
          if (FMAP) v = (v > 0.0f) ? (v + 1.0f) : __expf(v);  // elu(x)+1
          if (OUT == 1)
            reinterpret_cast<float*>(Cout)[(row0 + j) * NDIM + col] = v;
          else
            reinterpret_cast<unsigned short*>(Cout)[(row0 + j) * NDIM + col] = f2bf_bits(v);
        }
      }
    }
  }
}

// ---------------------------------------------------------------- kv + k_sum (MFMA, streaming)
// Inputs transposed: kT[bh][d][8192 t], vT[bh][e][8192 t] (bf16).
__global__ __launch_bounds__(256) void kv_ksum_mfma(
    const unsigned short* __restrict__ kT, const unsigned short* __restrict__ vT,
    float* __restrict__ kvT, float* __restrict__ ksum) {
  const int bid = blockIdx.x;
  const int bh = bid >> 4, ch = bid & 15;
  const int tid = threadIdx.x;
  const int lane = tid & 63, w = tid >> 6;
  const int l15 = lane & 15, lh = lane >> 4;
  const int dblk = (w >> 1) * 32, eblk = (w & 1) * 32;

  f32x4_t acc[2][2];
#pragma unroll
  for (int m = 0; m < 2; ++m)
#pragma unroll
    for (int n = 0; n < 2; ++n) acc[m][n] = (f32x4_t)0.0f;
  float ks0 = 0.f, ks1 = 0.f;

  const int tbase = ch * 512 + lh * 8;
  const unsigned short* ka = kT + (bh * 64 + dblk + l15) * 8192 + tbase;
  const unsigned short* va = vT + (bh * 64 + eblk + l15) * 8192 + tbase;

  for (int t0 = 0; t0 < 512; t0 += 32) {
    s16x8_t ar[2], br[2];
#pragma unroll
    for (int m = 0; m < 2; ++m)
      ar[m] = *reinterpret_cast<const s16x8_t*>(ka + m * 16 * 8192 + t0);
#pragma unroll
    for (int n = 0; n < 2; ++n)
      br[n] = *reinterpret_cast<const s16x8_t*>(va + n * 16 * 8192 + t0);
#pragma unroll
    for (int m = 0; m < 2; ++m)
#pragma unroll
      for (int n = 0; n < 2; ++n)
        acc[m][n] = __builtin_amdgcn_mfma_f32_16x16x32_bf16(
            __builtin_bit_cast(bf16x8_t, ar[m]),
            __builtin_bit_cast(bf16x8_t, br[n]), acc[m][n], 0, 0, 0);
    if (eblk == 0) {
#pragma unroll
      for (int i = 0; i < 8; ++i) ks0 += bf2f((unsigned short)ar[0][i]);
#pragma unroll
      for (int i = 0; i < 8; ++i) ks1 += bf2f((unsigned short)ar[1][i]);
    }
  }

  if (eblk == 0) {
    ks0 += __shfl_xor(ks0, 16); ks0 += __shfl_xor(ks0, 32);
    ks1 += __shfl_xor(ks1, 16); ks1 += __shfl_xor(ks1, 32);
    if (lh == 0) {
      atomicAdd(&ksum[bh * 64 + dblk + l15], ks0);
      atomicAdd(&ksum[bh * 64 + dblk + 16 + l15], ks1);
    }
  }
#pragma unroll
  for (int n = 0; n < 2; ++n) {
    const int e = eblk + n * 16 + l15;
#pragma unroll
    for (int m = 0; m < 2; ++m) {
      const int d0 = dblk + m * 16 + lh * 4;
#pragma unroll
      for (int j = 0; j < 4; ++j)
        atomicAdd(&kvT[(bh * 64 + e) * 64 + d0 + j], acc[m][n][j]);
    }
  }
}

// ---------------------------------------------------------------- out = q@kv / (q.ksum+eps)
__global__ __launch_bounds__(256) void attn_apply_kernel(
    const unsigned short* __restrict__ qf, const float* __restrict__ kvT,
    const float* __restrict__ ksum, unsigned short* __restrict__ att) {
  const int bid = blockIdx.x;                     // 2048
  const int swz = (bid & 7) * 256 + (bid >> 3);
  const int bh = swz >> 5;
  const int tile = swz & 31;
  const int b = bh >> 4, h = bh & 15;
  const int tid = threadIdx.x;
  const int lane = tid & 63, w = tid >> 6;
  const int l15 = lane & 15, lh = lane >> 4;

  float ksr[16];
#pragma unroll
  for (int i = 0; i < 16; ++i) ksr[i] = ksum[bh * 64 + lh * 16 + i];

  bf16x8_t bfrag[2][4];
#pragma unroll
  for (int ks2 = 0; ks2 < 2; ++ks2)
#pragma unroll
    for (int n = 0; n < 4; ++n) {
      const float* p = kvT + (bh * 64 + n * 16 + l15) * 64 + ks2 * 32 + lh * 8;
      f32x4_t p0 = *reinterpret_cast<const f32x4_t*>(p);
      f32x4_t p1 = *reinterpret_cast<const f32x4_t*>(p + 4);
      s16x8_t t;
      t[0] = (short)f2bf_bits(p0[0]); t[1] = (short)f2bf_bits(p0[1]);
      t[2] = (short)f2bf_bits(p0[2]); t[3] = (short)f2bf_bits(p0[3]);
      t[4] = (short)f2bf_bits(p1[0]); t[5] = (short)f2bf_bits(p1[1]);
      t[6] = (short)f2bf_bits(p1[2]); t[7] = (short)f2bf_bits(p1[3]);
      bfrag[ks2][n] = __builtin_bit_cast(bf16x8_t, t);
    }

  const int rbase = b * 8192 + tile * 256 + w * 64;
  f32x4_t acc[4][4];
#pragma unroll
  for (int m = 0; m < 4; ++m)
#pragma unroll
    for (int n = 0; n < 4; ++n) acc[m][n] = (f32x4_t)0.0f;
  float rden[4][4];

#pragma unroll
  for (int m = 0; m < 4; ++m) {
    const int row = rbase + m * 16 + l15;
    const unsigned short* qrow = qf + row * 1024 + h * 64;
    bf16x8_t afr[2];
#pragma unroll
    for (int ks2 = 0; ks2 < 2; ++ks2)
      afr[ks2] = __builtin_bit_cast(bf16x8_t,
          *reinterpret_cast<const s16x8_t*>(qrow + ks2 * 32 + lh * 8));
    s16x8_t qa = *reinterpret_cast<const s16x8_t*>(qrow + lh * 16);
    s16x8_t qb = *reinterpret_cast<const s16x8_t*>(qrow + lh * 16 + 8);
    float part = 0.f;
#pragma unroll
    for (int i = 0; i < 8; ++i) part += bf2f((unsigned short)qa[i]) * ksr[i];
#pragma unroll
    for (int i = 0; i < 8; ++i) part += bf2f((unsigned short)qb[i]) * ksr[8 + i];
    part += __shfl_xor(part, 16);
    part += __shfl_xor(part, 32);
#pragma unroll
    for (int j = 0; j < 4; ++j) {
      float dj = __shfl(part, lh * 4 + j);
      rden[m][j] = 1.0f / (dj + EPSV);
    }
#pragma unroll
    for (int ks2 = 0; ks2 < 2; ++ks2)
#pragma unroll
      for (int n = 0; n < 4; ++n)
        acc[m][n] = __builtin_amdgcn_mfma_f32_16x16x32_bf16(afr[ks2], bfrag[ks2][n], acc[m][n], 0, 0, 0);
  }

#pragma unroll
  for (int m = 0; m < 4; ++m)
#pragma unroll
    for (int n = 0; n < 4; ++n) {
      const int col = h * 64 + n * 16 + l15;
#pragma unroll
      for (int j = 0; j < 4; ++j) {
        const int row = rbase + m * 16 + lh * 4 + j;
        att[row * 1024 + col] = f2bf_bits(acc[m][n][j] * rden[m][j]);
      }
    }
}

// ---------------------------------------------------------------- launch
extern "C" void kernel_launch(void* const* d_in, const int* in_sizes, int n_in,
                              void* d_out, int out_size, void* d_ws, size_t ws_size,
                              hipStream_t stream) {
  const float* query = (const float*)d_in[0];
  const float* key   = (const float*)d_in[1];
  const float* value = (const float*)d_in[2];
  const float* Wq = (const float*)d_in[3];
  const float* bq = (const float*)d_in[4];
  const float* Wk = (const float*)d_in[5];
  const float* bk = (const float*)d_in[6];
  const float* Wv = (const float*)d_in[7];
  const float* bv = (const float*)d_in[8];
  const float* Wo = (const float*)d_in[9];
  const float* bo = (const float*)d_in[10];
  float* out = (float*)d_out;

  if (ws_size < 277889024ULL) return;
  char* ws = (char*)d_ws;
  unsigned short* Vbf = (unsigned short*)(ws + 0);          // value bf16; reused as att
  unsigned short* qf  = (unsigned short*)(ws + 67108864);
  unsigned short* kTf = (unsigned short*)(ws + 134217728);  // k transposed [b][h][d][t]
  unsigned short* vTf = (unsigned short*)(ws + 201326592);  // v transposed
  unsigned short* Wqb = (unsigned short*)(ws + 268435456);
  unsigned short* Wkb = Wqb + 1048576;
  unsigned short* Wvb = Wkb + 1048576;
  unsigned short* Wob = Wvb + 1048576;
  float* kvT  = (float*)(ws + 276824064);
  float* ksum = (float*)(ws + 277872640);

  unsigned short* Qbf = (unsigned short*)d_out;   // d_out doubles as bf16 scratch
  unsigned short* Kbf = Qbf + 33554432;

  hipMemsetAsync(kvT, 0, (size_t)(64 * 64 * 64 + 64 * 64) * sizeof(float), stream);

  convert3_f32_bf16<<<6144, 256, 0, stream>>>(query, key, value, Qbf, Kbf, Vbf);
  convertW_f32_bf16<<<2048, 256, 0, stream>>>(Wq, Wk, Wv, Wo, Wqb, Wkb, Wvb, Wob);

  gemm256<1, 0><<<512, 512, 0, stream>>>(Qbf, Wqb, bq, qf);   // q row-major
  gemm256<1, 2><<<512, 512, 0, stream>>>(Kbf, Wkb, bk, kTf);  // k transposed
  gemm256<0, 2><<<512, 512, 0, stream>>>(Vbf, Wvb, bv, vTf);  // v transposed

  kv_ksum_mfma<<<1024, 256, 0, stream>>>(kTf, vTf, kvT, ksum);

  attn_apply_kernel<<<2048, 256, 0, stream>>>(qf, kvT, ksum, Vbf);  // att -> Vbf

  gemm256<0, 1><<<512, 512, 0, stream>>>(Vbf, Wob, bo, out);  // final -> f32
}

// Round 6
// 570.774 us; speedup vs baseline: 1.3638x; 1.0518x over previous
//
#include <hip/hip_runtime.h>
#include <hip/hip_bf16.h>

typedef long long TLONG;
typedef float  f32x4_t  __attribute__((ext_vector_type(4)));
typedef short  s16x8_t  __attribute__((ext_vector_type(8)));
typedef short  s16x4_t  __attribute__((ext_vector_type(4)));
typedef __bf16 bf16x8_t __attribute__((ext_vector_type(8)));

#define MDIM 32768
#define NDIM 1024
#define KDIM 1024
#define EPSV 1e-6f

#define BARRIER() asm volatile("s_barrier" ::: "memory")
#define SBAR() __builtin_amdgcn_sched_barrier(0)

__device__ __forceinline__ unsigned short f2bf_bits(float f) {
  __hip_bfloat16 h = __float2bfloat16(f);
  return __builtin_bit_cast(unsigned short, h);
}
__device__ __forceinline__ float bf2f(unsigned short u) {
  unsigned int x = ((unsigned int)u) << 16;
  return __builtin_bit_cast(float, x);
}
// async global->LDS, 16B per lane. LDS dest must be wave-uniform base + lane*16.
__device__ __forceinline__ void load_lds16(const void* g, void* l) {
  __builtin_amdgcn_global_load_lds((const __attribute__((address_space(1))) void*)g,
                                   (__attribute__((address_space(3))) void*)l, 16, 0, 0);
}

// ---------------------------------------------------------------- weight convert
// 4 weights (1M elems each), 2048 blocks: 512*256*8 = exactly 1M per range
__global__ __launch_bounds__(256) void convertW_f32_bf16(
    const float* __restrict__ a, const float* __restrict__ b, const float* __restrict__ c,
    const float* __restrict__ d, unsigned short* __restrict__ oa,
    unsigned short* __restrict__ ob, unsigned short* __restrict__ oc,
    unsigned short* __restrict__ od) {
  int blk = blockIdx.x;
  const float* in; unsigned short* out;
  if (blk < 512)       { in = a; out = oa; }
  else if (blk < 1024) { in = b; out = ob; blk -= 512; }
  else if (blk < 1536) { in = c; out = oc; blk -= 1024; }
  else                 { in = d; out = od; blk -= 1536; }
  TLONG i = ((TLONG)blk * 256 + threadIdx.x) * 8;
  f32x4_t x = *reinterpret_cast<const f32x4_t*>(in + i);
  f32x4_t y = *reinterpret_cast<const f32x4_t*>(in + i + 4);
  s16x8_t o;
  o[0] = (short)f2bf_bits(x[0]); o[1] = (short)f2bf_bits(x[1]);
  o[2] = (short)f2bf_bits(x[2]); o[3] = (short)f2bf_bits(x[3]);
  o[4] = (short)f2bf_bits(y[0]); o[5] = (short)f2bf_bits(y[1]);
  o[6] = (short)f2bf_bits(y[2]); o[7] = (short)f2bf_bits(y[3]);
  *reinterpret_cast<s16x8_t*>(out + i) = o;
}

// ---------------------------------------------------------------- GEMM 256x256, counted-wait phases
// C[m][n] = f(sum_k A[m][k]*W[n][k] + bias[n]); M=32768, N=K=1024.
// BM=BN=256, BK=64; 512 thr = 8 waves (2M x 4N); wave tile 128x64.
// LDS 128 KiB = 2 buf x (A 32KB | B 32KB). W always bf16 via global_load_lds.
// AF32=0: A bf16 via global_load_lds (R5-proven schedule, quads (0,0),(4,0),(0,2),(4,2)).
// AF32=1: A f32 reg-staged with fused cvt (convert kernel eliminated).
//   phA: LOAD A(kt+2)->regs(8 vmem); vmcnt(8) retires B(kt) gloads; 12+4 pinned
//        ds_reads; gload Bh0(kt+1); bar; lgkm(4); quad(0,0); bar
//   phB: gload Bh1(kt+1); bar; lgkm(0); quad(0,2); bar      [Af0-3 regs die]
//   phC: ds_reads Af4-7; bar; lgkm(0); quad(4,0); bar
//   phD: vmcnt(4) [A landed, B gloads stay in flight - T4]; cvt+ds_write A into
//        buf p; quad(4,2); lgkm(0) [writes drained -> clean counters]; bar
template <int FMAP, int OUT, int AF32>
__global__ __launch_bounds__(512, 2) void gemm256(
    const void* __restrict__ Ain, const unsigned short* __restrict__ W,
    const float* __restrict__ bias, void* __restrict__ Cout) {
  __shared__ short lds[65536];                    // [2 buf][A 16384 | B 16384] shorts
  const int bid = blockIdx.x;                     // 512 blocks
  const int swz = (bid & 7) * 64 + (bid >> 3);    // XCD-chunked (512%8==0)
  const int mt = swz >> 2;                        // 0..127
  const int nt = swz & 3;                         // 0..3

  const int tid = threadIdx.x;
  const int lane = tid & 63;
  const int w = tid >> 6;
  const int wr = w >> 2, wc = w & 3;
  const int l15 = lane & 15, lh = lane >> 4;

  const int arow0 = mt * 256, brow0 = nt * 256;

  const unsigned short* Ab = (const unsigned short*)Ain;  // AF32=0
  const float* Af32 = (const float*)Ain;                  // AF32=1

  // gload one 128-row half (bf16 src), linear LDS dest, pre-swizzled source
  auto stage_half_g = [&](const unsigned short* __restrict__ src, int ldsOff,
                          int grow, int k0) {
#pragma unroll
    for (int i = 0; i < 2; ++i) {
      const int c = i * 512 + tid;                // 0..1023
      const int r = c >> 3, ps = c & 7;
      load_lds16(src + (grow + r) * KDIM + k0 + ((ps ^ (r & 7)) * 8),
                 &lds[ldsOff + c * 8]);
    }
  };

  // A f32 reg-staging (AF32=1): 4 chunks x 8 f32 = 32 VGPR in flight
  f32x4_t Ast[4][2];
  auto loadA = [&](int k0) {
#pragma unroll
    for (int h = 0; h < 2; ++h)
#pragma unroll
      for (int i = 0; i < 2; ++i) {
        const int c = i * 512 + tid;
        const int r = c >> 3, ps = c & 7;
        const float* gp = Af32 + (arow0 + h * 128 + r) * KDIM + k0 + ((ps ^ (r & 7)) * 8);
        Ast[h * 2 + i][0] = *reinterpret_cast<const f32x4_t*>(gp);
        Ast[h * 2 + i][1] = *reinterpret_cast<const f32x4_t*>(gp + 4);
      }
  };
  auto writeA = [&](int abase) {                  // abase = buf A region (shorts)
#pragma unroll
    for (int h = 0; h < 2; ++h)
#pragma unroll
      for (int i = 0; i < 2; ++i) {
        const int c = i * 512 + tid;
        s16x8_t o;
#pragma unroll
        for (int j = 0; j < 4; ++j) {
          o[j]     = (short)f2bf_bits(Ast[h * 2 + i][0][j]);
          o[4 + j] = (short)f2bf_bits(Ast[h * 2 + i][1][j]);
        }
        *reinterpret_cast<s16x8_t*>(&lds[abase + h * 8192 + c * 8]) = o;
      }
  };

  f32x4_t acc[8][4];
#pragma unroll
  for (int m = 0; m < 8; ++m)
#pragma unroll
    for (int n = 0; n < 4; ++n) acc[m][n] = (f32x4_t)0.0f;

  s16x8_t Af[8][2], Bf[4][2];

  auto rdA = [&](int pb, int m, int ks) -> s16x8_t {
    const int row = wr * 128 + m * 16 + l15;
    return *reinterpret_cast<const s16x8_t*>(
        &lds[pb + row * 64 + (((ks * 4 + lh) ^ (row & 7)) * 8)]);
  };
  auto rdB = [&](int pb, int n, int ks) -> s16x8_t {
    const int row = wc * 64 + n * 16 + l15;
    return *reinterpret_cast<const s16x8_t*>(
        &lds[pb + 16384 + row * 64 + (((ks * 4 + lh) ^ (row & 7)) * 8)]);
  };
  auto quad = [&](int mb, int nl) {
    __builtin_amdgcn_s_setprio(1);
#pragma unroll
    for (int m = 0; m < 4; ++m)
#pragma unroll
      for (int n = 0; n < 2; ++n)
#pragma unroll
        for (int ks = 0; ks < 2; ++ks)
          acc[mb + m][nl + n] = __builtin_amdgcn_mfma_f32_16x16x32_bf16(
              __builtin_bit_cast(bf16x8_t, Af[mb + m][ks]),
              __builtin_bit_cast(bf16x8_t, Bf[nl + n][ks]),
              acc[mb + m][nl + n], 0, 0, 0);
    __builtin_amdgcn_s_setprio(0);
  };

  if constexpr (AF32 == 1) {
    // ---- prologue: A0,A1 via reg-stage; B0 via gload
    loadA(0);                                          // 8 vmem
    stage_half_g(W, 16384, brow0, 0);                  // B0h0: 2 vmem
    stage_half_g(W, 16384 + 8192, brow0 + 128, 0);     // B0h1: 2 vmem
    asm volatile("s_waitcnt vmcnt(4)" ::: "memory");   // A0 landed
    SBAR();
    writeA(0);                                         // buf0 A
    loadA(64);                                         // A1: 8 vmem
    asm volatile("s_waitcnt vmcnt(0)" ::: "memory");   // drain (prologue only)
    SBAR();
    writeA(32768);                                     // buf1 A
    asm volatile("s_waitcnt lgkmcnt(0)" ::: "memory");
    SBAR();
    BARRIER();

    for (int kt = 0; kt < 16; ++kt) {
      const int p = kt & 1;
      const int pb = p * 32768, qb = 32768 - pb;
      const int k1 = ((kt + 1) & 15) * 64;
      const int k2 = ((kt + 2) & 15) * 64;   // wrapped tail: junk reload, never read
      // ---- phase A
      loadA(k2);                                       // 8 vmem (oldest after retire)
      SBAR();
      asm volatile("s_waitcnt vmcnt(8)" ::: "memory"); // B(kt) gloads retired
      SBAR();
#pragma unroll
      for (int m = 0; m < 4; ++m)
#pragma unroll
        for (int ks = 0; ks < 2; ++ks) Af[m][ks] = rdA(pb, m, ks);
#pragma unroll
      for (int n = 0; n < 2; ++n)
#pragma unroll
        for (int ks = 0; ks < 2; ++ks) Bf[n][ks] = rdB(pb, n, ks);
      SBAR();                                          // group 1 (12 reads)
#pragma unroll
      for (int n = 2; n < 4; ++n)
#pragma unroll
        for (int ks = 0; ks < 2; ++ks) Bf[n][ks] = rdB(pb, n, ks);
      SBAR();                                          // group 2 (4 reads)
      stage_half_g(W, qb + 16384, brow0, k1);          // Bh0(kt+1)
      BARRIER();
      asm volatile("s_waitcnt lgkmcnt(4)" ::: "memory");   // group 1 done
      SBAR();
      quad(0, 0);
      BARRIER();
      // ---- phase B
      stage_half_g(W, qb + 16384 + 8192, brow0 + 128, k1); // Bh1(kt+1)
      BARRIER();
      asm volatile("s_waitcnt lgkmcnt(0)" ::: "memory");   // all 16 reads done
      SBAR();
      quad(0, 2);
      BARRIER();
      // ---- phase C
#pragma unroll
      for (int m = 0; m < 4; ++m)
#pragma unroll
        for (int ks = 0; ks < 2; ++ks) Af[4 + m][ks] = rdA(pb, 4 + m, ks);
      BARRIER();
      asm volatile("s_waitcnt lgkmcnt(0)" ::: "memory");
      SBAR();
      quad(4, 0);
      BARRIER();
      // ---- phase D
      asm volatile("s_waitcnt vmcnt(4)" ::: "memory");     // A(kt+2) landed
      SBAR();
      writeA(pb);                                          // kt+2 parity == p
      quad(4, 2);
      asm volatile("s_waitcnt lgkmcnt(0)" ::: "memory");   // drain ds_writes
      SBAR();
      BARRIER();
    }
  } else {
    // ---- R5-proven all-gload path (A bf16)
    stage_half_g(Ab, 0,             arow0,       0);
    stage_half_g(Ab, 8192,          arow0 + 128, 0);
    stage_half_g(W,  16384,         brow0,       0);
    stage_half_g(W,  16384 + 8192,  brow0 + 128, 0);
    stage_half_g(Ab, 32768,         arow0,       64);
    stage_half_g(Ab, 32768 + 8192,  arow0 + 128, 64);
    asm volatile("s_waitcnt vmcnt(4)" ::: "memory");
    SBAR();
    BARRIER();

    for (int kt = 0; kt < 16; ++kt) {
      const int p = kt & 1;
      const int pb = p * 32768, qb = 32768 - pb;
      const int k1 = ((kt + 1) & 15) * 64;
      const int k2 = ((kt + 2) & 15) * 64;
      // ---- phase A: all 24 ds_reads (pinned groups); stage (kt+1).Bh0
#pragma unroll
      for (int m = 0; m < 4; ++m)
#pragma unroll
        for (int ks = 0; ks < 2; ++ks) Af[m][ks] = rdA(pb, m, ks);
#pragma unroll
      for (int n = 0; n < 2; ++n)
#pragma unroll
        for (int ks = 0; ks < 2; ++ks) Bf[n][ks] = rdB(pb, n, ks);
      SBAR();
#pragma unroll
      for (int m = 0; m < 4; ++m)
#pragma unroll
        for (int ks = 0; ks < 2; ++ks) Af[4 + m][ks] = rdA(pb, 4 + m, ks);
      SBAR();
#pragma unroll
      for (int n = 2; n < 4; ++n)
#pragma unroll
        for (int ks = 0; ks < 2; ++ks) Bf[n][ks] = rdB(pb, n, ks);
      SBAR();
      stage_half_g(W, qb + 16384, brow0, k1);
      BARRIER();
      asm volatile("s_waitcnt lgkmcnt(12)" ::: "memory");
      SBAR();
      quad(0, 0);
      BARRIER();
      // ---- phase B
      stage_half_g(W, qb + 16384 + 8192, brow0 + 128, k1);
      BARRIER();
      asm volatile("s_waitcnt lgkmcnt(4)" ::: "memory");
      SBAR();
      quad(4, 0);
      BARRIER();
      // ---- phase C
      stage_half_g(Ab, pb, arow0, k2);
      BARRIER();
      asm volatile("s_waitcnt lgkmcnt(0)" ::: "memory");
      SBAR();
      quad(0, 2);
      BARRIER();
      // ---- phase D
      stage_half_g(Ab, pb + 8192, arow0 + 128, k2);
      BARRIER();
      quad(4, 2);
      asm volatile("s_waitcnt vmcnt(4)" ::: "memory");
      SBAR();
      BARRIER();
    }
  }

  // epilogue: C/D layout col = lane&15, row = (lane>>4)*4 + j  [m89/m91]
#pragma unroll
  for (int n = 0; n < 4; ++n) {
    const int col = nt * 256 + wc * 64 + n * 16 + l15;
    const float bv = bias[col];
#pragma unroll
    for (int m = 0; m < 8; ++m) {
      const int row0 = mt * 256 + wr * 128 + m * 16 + lh * 4;
      if (OUT == 2) {
        const int b = row0 >> 13, tl = row0 & 8191;
        const int h = col >> 6, d = col & 63;
        s16x4_t o;
#pragma unroll
        for (int j = 0; j < 4; ++j) {
          float v = acc[m][n][j] + bv;
          if (FMAP) v = (v > 0.0f) ? (v + 1.0f) : __expf(v);
          o[j] = (short)f2bf_bits(v);
        }
        *reinterpret_cast<s16x4_t*>(
            reinterpret_cast<unsigned short*>(Cout) +
            (((b * 16 + h) * 64 + d) * 8192 + tl)) = o;
      } else {
#pragma unroll
        for (int j = 0; j < 4; ++j) {
          float v = acc[m][n][j] + bv;
          if (FMAP) v = (v > 0.0f) ? (v + 1.0f) : __expf(v);  // elu(x)+1
          if (OUT == 1)
            reinterpret_cast<float*>(Cout)[(row0 + j) * NDIM + col] = v;
          else
            reinterpret_cast<unsigned short*>(Cout)[(row0 + j) * NDIM + col] = f2bf_bits(v);
        }
      }
    }
  }
}

// ---------------------------------------------------------------- kv + k_sum (MFMA, streaming)
// Inputs transposed: kT[bh][d][8192 t], vT[bh][e][8192 t] (bf16).
__global__ __launch_bounds__(256) void kv_ksum_mfma(
    const unsigned short* __restrict__ kT, const unsigned short* __restrict__ vT,
    float* __restrict__ kvT, float* __restrict__ ksum) {
  const int bid = blockIdx.x;
  const int bh = bid >> 4, ch = bid & 15;
  const int tid = threadIdx.x;
  const int lane = tid & 63, w = tid >> 6;
  const int l15 = lane & 15, lh = lane >> 4;
  const int dblk = (w >> 1) * 32, eblk = (w & 1) * 32;

  f32x4_t acc[2][2];
#pragma unroll
  for (int m = 0; m < 2; ++m)
#pragma unroll
    for (int n = 0; n < 2; ++n) acc[m][n] = (f32x4_t)0.0f;
  float ks0 = 0.f, ks1 = 0.f;

  const int tbase = ch * 512 + lh * 8;
  const unsigned short* ka = kT + (bh * 64 + dblk + l15) * 8192 + tbase;
  const unsigned short* va = vT + (bh * 64 + eblk + l15) * 8192 + tbase;

  for (int t0 = 0; t0 < 512; t0 += 32) {
    s16x8_t ar[2], br[2];
#pragma unroll
    for (int m = 0; m < 2; ++m)
      ar[m] = *reinterpret_cast<const s16x8_t*>(ka + m * 16 * 8192 + t0);
#pragma unroll
    for (int n = 0; n < 2; ++n)
      br[n] = *reinterpret_cast<const s16x8_t*>(va + n * 16 * 8192 + t0);
#pragma unroll
    for (int m = 0; m < 2; ++m)
#pragma unroll
      for (int n = 0; n < 2; ++n)
        acc[m][n] = __builtin_amdgcn_mfma_f32_16x16x32_bf16(
            __builtin_bit_cast(bf16x8_t, ar[m]),
            __builtin_bit_cast(bf16x8_t, br[n]), acc[m][n], 0, 0, 0);
    if (eblk == 0) {
#pragma unroll
      for (int i = 0; i < 8; ++i) ks0 += bf2f((unsigned short)ar[0][i]);
#pragma unroll
      for (int i = 0; i < 8; ++i) ks1 += bf2f((unsigned short)ar[1][i]);
    }
  }

  if (eblk == 0) {
    ks0 += __shfl_xor(ks0, 16); ks0 += __shfl_xor(ks0, 32);
    ks1 += __shfl_xor(ks1, 16); ks1 += __shfl_xor(ks1, 32);
    if (lh == 0) {
      atomicAdd(&ksum[bh * 64 + dblk + l15], ks0);
      atomicAdd(&ksum[bh * 64 + dblk + 16 + l15], ks1);
    }
  }
#pragma unroll
  for (int n = 0; n < 2; ++n) {
    const int e = eblk + n * 16 + l15;
#pragma unroll
    for (int m = 0; m < 2; ++m) {
      const int d0 = dblk + m * 16 + lh * 4;
#pragma unroll
      for (int j = 0; j < 4; ++j)
        atomicAdd(&kvT[(bh * 64 + e) * 64 + d0 + j], acc[m][n][j]);
    }
  }
}

// ---------------------------------------------------------------- out = q@kv / (q.ksum+eps)
__global__ __launch_bounds__(256) void attn_apply_kernel(
    const unsigned short* __restrict__ qf, const float* __restrict__ kvT,
    const float* __restrict__ ksum, unsigned short* __restrict__ att) {
  const int bid = blockIdx.x;                     // 2048
  const int swz = (bid & 7) * 256 + (bid >> 3);
  const int bh = swz >> 5;
  const int tile = swz & 31;
  const int b = bh >> 4, h = bh & 15;
  const int tid = threadIdx.x;
  const int lane = tid & 63, w = tid >> 6;
  const int l15 = lane & 15, lh = lane >> 4;

  float ksr[16];
#pragma unroll
  for (int i = 0; i < 16; ++i) ksr[i] = ksum[bh * 64 + lh * 16 + i];

  bf16x8_t bfrag[2][4];
#pragma unroll
  for (int ks2 = 0; ks2 < 2; ++ks2)
#pragma unroll
    for (int n = 0; n < 4; ++n) {
      const float* p = kvT + (bh * 64 + n * 16 + l15) * 64 + ks2 * 32 + lh * 8;
      f32x4_t p0 = *reinterpret_cast<const f32x4_t*>(p);
      f32x4_t p1 = *reinterpret_cast<const f32x4_t*>(p + 4);
      s16x8_t t;
      t[0] = (short)f2bf_bits(p0[0]); t[1] = (short)f2bf_bits(p0[1]);
      t[2] = (short)f2bf_bits(p0[2]); t[3] = (short)f2bf_bits(p0[3]);
      t[4] = (short)f2bf_bits(p1[0]); t[5] = (short)f2bf_bits(p1[1]);
      t[6] = (short)f2bf_bits(p1[2]); t[7] = (short)f2bf_bits(p1[3]);
      bfrag[ks2][n] = __builtin_bit_cast(bf16x8_t, t);
    }

  const int rbase = b * 8192 + tile * 256 + w * 64;
  f32x4_t acc[4][4];
#pragma unroll
  for (int m = 0; m < 4; ++m)
#pragma unroll
    for (int n = 0; n < 4; ++n) acc[m][n] = (f32x4_t)0.0f;
  float rden[4][4];

#pragma unroll
  for (int m = 0; m < 4; ++m) {
    const int row = rbase + m * 16 + l15;
    const unsigned short* qrow = qf + row * 1024 + h * 64;
    bf16x8_t afr[2];
#pragma unroll
    for (int ks2 = 0; ks2 < 2; ++ks2)
      afr[ks2] = __builtin_bit_cast(bf16x8_t,
          *reinterpret_cast<const s16x8_t*>(qrow + ks2 * 32 + lh * 8));
    s16x8_t qa = *reinterpret_cast<const s16x8_t*>(qrow + lh * 16);
    s16x8_t qb = *reinterpret_cast<const s16x8_t*>(qrow + lh * 16 + 8);
    float part = 0.f;
#pragma unroll
    for (int i = 0; i < 8; ++i) part += bf2f((unsigned short)qa[i]) * ksr[i];
#pragma unroll
    for (int i = 0; i < 8; ++i) part += bf2f((unsigned short)qb[i]) * ksr[8 + i];
    part += __shfl_xor(part, 16);
    part += __shfl_xor(part, 32);
#pragma unroll
    for (int j = 0; j < 4; ++j) {
      float dj = __shfl(part, lh * 4 + j);
      rden[m][j] = 1.0f / (dj + EPSV);
    }
#pragma unroll
    for (int ks2 = 0; ks2 < 2; ++ks2)
#pragma unroll
      for (int n = 0; n < 4; ++n)
        acc[m][n] = __builtin_amdgcn_mfma_f32_16x16x32_bf16(afr[ks2], bfrag[ks2][n], acc[m][n], 0, 0, 0);
  }

#pragma unroll
  for (int m = 0; m < 4; ++m)
#pragma unroll
    for (int n = 0; n < 4; ++n) {
      const int col = h * 64 + n * 16 + l15;
#pragma unroll
      for (int j = 0; j < 4; ++j) {
        const int row = rbase + m * 16 + lh * 4 + j;
        att[row * 1024 + col] = f2bf_bits(acc[m][n][j] * rden[m][j]);
      }
    }
}

// ---------------------------------------------------------------- launch
extern "C" void kernel_launch(void* const* d_in, const int* in_sizes, int n_in,
                              void* d_out, int out_size, void* d_ws, size_t ws_size,
                              hipStream_t stream) {
  const float* query = (const float*)d_in[0];
  const float* key   = (const float*)d_in[1];
  const float* value = (const float*)d_in[2];
  const float* Wq = (const float*)d_in[3];
  const float* bq = (const float*)d_in[4];
  const float* Wk = (const float*)d_in[5];
  const float* bk = (const float*)d_in[6];
  const float* Wv = (const float*)d_in[7];
  const float* bv = (const float*)d_in[8];
  const float* Wo = (const float*)d_in[9];
  const float* bo = (const float*)d_in[10];
  float* out = (float*)d_out;

  if (ws_size < 277889024ULL) return;
  char* ws = (char*)d_ws;
  unsigned short* att = (unsigned short*)(ws + 0);          // att bf16 (row-major)
  unsigned short* qf  = (unsigned short*)(ws + 67108864);
  unsigned short* kTf = (unsigned short*)(ws + 134217728);  // k transposed [b][h][d][t]
  unsigned short* vTf = (unsigned short*)(ws + 201326592);  // v transposed
  unsigned short* Wqb = (unsigned short*)(ws + 268435456);
  unsigned short* Wkb = Wqb + 1048576;
  unsigned short* Wvb = Wkb + 1048576;
  unsigned short* Wob = Wvb + 1048576;
  float* kvT  = (float*)(ws + 276824064);
  float* ksum = (float*)(ws + 277872640);

  hipMemsetAsync(kvT, 0, (size_t)(64 * 64 * 64 + 64 * 64) * sizeof(float), stream);

  convertW_f32_bf16<<<2048, 256, 0, stream>>>(Wq, Wk, Wv, Wo, Wqb, Wkb, Wvb, Wob);

  gemm256<1, 0, 1><<<512, 512, 0, stream>>>(query, Wqb, bq, qf);   // q = fmap(query@Wq^T)
  gemm256<1, 2, 1><<<512, 512, 0, stream>>>(key,   Wkb, bk, kTf);  // k transposed
  gemm256<0, 2, 1><<<512, 512, 0, stream>>>(value, Wvb, bv, vTf);  // v transposed

  kv_ksum_mfma<<<1024, 256, 0, stream>>>(kTf, vTf, kvT, ksum);

  attn_apply_kernel<<<2048, 256, 0, stream>>>(qf, kvT, ksum, att);

  gemm256<0, 1, 0><<<512, 512, 0, stream>>>(att, Wob, bo, out);    // final -> f32
}